// Round 7
// baseline (914.651 us; speedup 1.0000x reference)
//
#include <hip/hip_runtime.h>
#include <math.h>

#define BATCH 512
#define ITERS 1000
#define PLEN 25      // iterations per phase
#define PHASES 40    // producer phase p covers k = 25p+1 .. 25p+25

typedef float f32x2 __attribute__((ext_vector_type(2)));
typedef float f32x4 __attribute__((ext_vector_type(4)));

// readlane requires a WAVE-UNIFORM lane index (compile-time constants below).
__device__ __forceinline__ float rdlane(float v, int l) {
  return __int_as_float(__builtin_amdgcn_readlane(__float_as_int(v), l));
}
__device__ __forceinline__ f32x2 fma2(f32x2 a, f32x2 b, f32x2 c) {
#if __has_builtin(__builtin_elementwise_fma)
  return __builtin_elementwise_fma(a, b, c);
#else
  f32x2 r; r.x = fmaf(a.x, b.x, c.x); r.y = fmaf(a.y, b.y, c.y); return r;
#endif
}
// Exchange a float with partner lane (lane^32), VALU pipe (no LDS).
// v_permlane32_swap_b32 swaps one half of vdst with the opposite half of
// vsrc; with a=b=v the per-lane result set is {own, partner} regardless of
// which operand receives which half (v7 failed by assuming the order).
// partner = a' + b' - v is correct under either convention. The movs are
// earlyclobber so a,b are distinct regs and neither aliases v (the swap
// must not corrupt v, which is read afterwards).
__device__ __forceinline__ float xchg32(float v) {
  float a, b;
  asm("v_mov_b32 %0, %2\n\tv_mov_b32 %1, %2" : "=&v"(a), "=&v"(b) : "v"(v));
  asm volatile("v_permlane32_swap_b32 %0, %1" : "+v"(a), "+v"(b));
  return (a + b) - v;
}

// sD row `lane` stored as 32 packed f32x2 (for v_pk_fma_f32). Element access
// (all indices compile-time constants in unrolled loops):
#define DC(c) (((c) & 1) ? dcol2[(c) >> 1].y : dcol2[(c) >> 1].x)

// Register-resident Gauss-Jordan on [A|I] (32x64); lane holds column `lane`.
#define GJ32_REG(g)                                            \
  _Pragma("unroll")                                            \
  for (int k = 0; k < 32; ++k) {                               \
    float inv = 1.0f / rdlane(g[k], k);                        \
    g[k] *= inv;                                               \
    _Pragma("unroll")                                          \
    for (int ii = 0; ii < 32; ++ii) {                          \
      if (ii == k) continue;                                   \
      float f = rdlane(g[ii], k);                              \
      g[ii] = fmaf(-f, g[k], g[ii]);                           \
    }                                                          \
  }

// wave 0 = iterator, wave 1 = consumer (Xs stores + primal GEMV + store).
// v8 = v7 with the exchange fixed (see xchg32). Theory under test: the
// per-CU LDS pipe is ~80% occupied (v3: ~15.6k DS cyc of the 19.7k cyc
// phase). Iterator broadcast halved: each half-wave reads only ITS 32 x1
// components (8 ds_read_b128, 2-addr broadcast = free 2-way). Lane l
// computes dots for row l AND row l^32 over its half; one permlane32 swap
// (VALU) exchanges the cross partial. Row l^32 coefficients from a one-time
// setup exchange (D symmetric). v3's register-array prefetch skeleton kept
// verbatim (v6 showed inline reads destroy scheduling).
__global__ __launch_bounds__(128, 1)
void fused_kernel(const float* __restrict__ q,
                  const float* __restrict__ bmat,
                  const float* __restrict__ P,
                  const float* __restrict__ H,
                  float* __restrict__ Xs,
                  float* __restrict__ out2) {
  __shared__ __align__(16) float stage[2112];        // wave 1: Hl 64x33 -> HT 32x66
  __shared__ __align__(16) float X1R[2][PLEN][64];   // ring: x1
  __shared__ __align__(16) float X2R[2][PLEN][64];   // ring: x2 - b

  const int tid = threadIdx.x;
  const int wv = tid >> 6;          // 0 = iterator, 1 = consumer
  const int lane = tid & 63;
  const int row = blockIdx.x;
  const int i = lane & 31, h = lane >> 5;

  // ---- H row `lane` (both waves need it) ----
  float hreg[32];
  {
    const f32x4* hp = (const f32x4*)(H + lane * 32);
    #pragma unroll
    for (int j4 = 0; j4 < 8; ++j4) {
      f32x4 t = hp[j4];
      hreg[4*j4+0] = t.x; hreg[4*j4+1] = t.y; hreg[4*j4+2] = t.z; hreg[4*j4+3] = t.w;
    }
  }
  const float bl = bmat[row * 64 + lane];

  f32x2 dcol2[32];                  // setup: row `lane` of sD (packed)
  f32x2 dA[16], dB[16];             // main loop: rows `lane`,`lane^32`, own half
  float s = 0.f, mu = 0.f;
  f32x4 xb[8];                      // broadcast x1 own half (iterator)
  float x1 = 0.f, x2 = 0.f;
  f32x2 hv2[16];                    // consumer state
  float* Xp = Xs + (size_t)row * (ITERS + 1) * 128;
  float* ob = out2 + (size_t)row * (ITERS + 1) * 32;

  // ---------- wave-1 Hinv transpose (block-wide barriers B1..B3) ----------
  if (wv == 1) {
    #pragma unroll
    for (int j = 0; j < 32; ++j) stage[lane * 33 + j] = hreg[j];
  }
  __syncthreads();                                // B1
  float gB[32];
  if (wv == 1) {
    float htc[64];                                // htc[m] = H[m][i]
    #pragma unroll
    for (int m = 0; m < 64; ++m) htc[m] = stage[m * 33 + i];
    #pragma unroll
    for (int r = 0; r < 32; ++r) {
      float a0 = 0.f, a1 = 0.f;
      #pragma unroll
      for (int m = 0; m < 64; m += 2) {
        a0 = fmaf(rdlane(hreg[r], m),     htc[m],     a0);
        a1 = fmaf(rdlane(hreg[r], m + 1), htc[m + 1], a1);
      }
      float hth = a0 + a1;                        // (H^T H)[r][i]
      gB[r] = (lane < 32) ? hth : (((lane - 32) == r) ? 1.0f : 0.0f);
    }
    GJ32_REG(gB)
  }
  __syncthreads();                                // B2
  if (wv == 1) {
    #pragma unroll
    for (int r = 0; r < 32; ++r) {                // Hinv[r][lane] -> staging
      float a0 = 0.f, a1 = 0.f;
      #pragma unroll
      for (int c = 0; c < 32; c += 2) {
        a0 = fmaf(rdlane(gB[r], 32 + c),     hreg[c],     a0);
        a1 = fmaf(rdlane(gB[r], 32 + c + 1), hreg[c + 1], a1);
      }
      stage[r * 66 + lane] = a0 + a1;
    }
  }
  __syncthreads();                                // B3
  if (wv == 1) {
    #pragma unroll
    for (int t = 0; t < 16; ++t)                  // lane (h,i): Hinv[i][32h+2t..+1]
      hv2[t] = *(const f32x2*)&stage[i * 66 + 32 * h + 2 * t];
  }

  if (wv == 0) {
    // ---------- setup (registers only): P^-1, P^-1 H^T, D, lambda_max ----------
    float pht[32], acc;
    {
      float g[32];
      #pragma unroll
      for (int r = 0; r < 32; ++r) {
        float pv = P[r * 32 + i];
        g[r] = (lane < 32) ? pv : (((lane - 32) == r) ? 1.0f : 0.0f);
      }
      GJ32_REG(g)
      #pragma unroll
      for (int r = 0; r < 32; ++r) {      // (P^-1 H^T)[r][lane]
        float a0 = 0.f, a1 = 0.f;
        #pragma unroll
        for (int j = 0; j < 32; j += 2) {
          a0 = fmaf(rdlane(g[r], 32 + j),     hreg[j],     a0);
          a1 = fmaf(rdlane(g[r], 32 + j + 1), hreg[j + 1], a1);
        }
        pht[r] = a0 + a1;
      }
    }
    {
      const float* qp = q + row * 32;     // wave-uniform -> s_loads
      float a0 = 0.f, a1 = 0.f;
      #pragma unroll
      for (int r = 0; r < 32; r += 2) {
        a0 = fmaf(qp[r],     pht[r],     a0);
        a1 = fmaf(qp[r + 1], pht[r + 1], a1);
      }
      acc = a0 + a1;                      // (H P^-1 q)[lane]
    }
    #pragma unroll
    for (int r = 0; r < 64; ++r) {        // D[r][lane] (symmetric)
      float a0 = 0.f, a1 = 0.f;
      #pragma unroll
      for (int j = 0; j < 32; j += 2) {
        a0 = fmaf(rdlane(hreg[j],     r), pht[j],     a0);
        a1 = fmaf(rdlane(hreg[j + 1], r), pht[j + 1], a1);
      }
      float val = a0 + a1;
      if (r & 1) dcol2[r >> 1].y = val; else dcol2[r >> 1].x = val;
    }
    {
      float ecol[64];                     // E = D^2 (squares convergence rate)
      #pragma unroll
      for (int r = 0; r < 64; ++r) {
        float a0 = 0.f, a1 = 0.f;
        #pragma unroll
        for (int c = 0; c < 64; c += 2) {
          a0 = fmaf(rdlane(DC(r), c),     DC(c),     a0);
          a1 = fmaf(rdlane(DC(r), c + 1), DC(c + 1), a1);
        }
        ecol[r] = a0 + a1;
      }
      float v = 1.0f + 0.017f * (float)lane;
      #pragma unroll 1
      for (int t = 0; t < 112; ++t) {
        float a0 = 0.f, a1 = 0.f, a2 = 0.f, a3 = 0.f;
        #pragma unroll
        for (int c = 0; c < 64; c += 4) {
          a0 = fmaf(ecol[c+0], rdlane(v, c+0), a0);
          a1 = fmaf(ecol[c+1], rdlane(v, c+1), a1);
          a2 = fmaf(ecol[c+2], rdlane(v, c+2), a2);
          a3 = fmaf(ecol[c+3], rdlane(v, c+3), a3);
        }
        v = (a0 + a1) + (a2 + a3);
        if ((t & 7) == 7) {
          float n2 = v * v;
          #pragma unroll
          for (int m = 1; m < 64; m <<= 1) n2 += __shfl_xor(n2, m);
          v *= 1.0f / sqrtf(n2);
        }
      }
      float a0 = 0.f, a1 = 0.f, a2 = 0.f, a3 = 0.f;  // Rayleigh with D
      #pragma unroll
      for (int c = 0; c < 64; c += 4) {
        a0 = fmaf(DC(c+0), rdlane(v, c+0), a0);
        a1 = fmaf(DC(c+1), rdlane(v, c+1), a1);
        a2 = fmaf(DC(c+2), rdlane(v, c+2), a2);
        a3 = fmaf(DC(c+3), rdlane(v, c+3), a3);
      }
      float w = (a0 + a1) + (a2 + a3);
      float num = w * v, den = v * v;
      #pragma unroll
      for (int m = 1; m < 64; m <<= 1) {
        num += __shfl_xor(num, m);
        den += __shfl_xor(den, m);
      }
      s = den / num;                      // s = 1 / lambda_max(D)
    }
    mu = s * (acc - bl);
    #pragma unroll
    for (int t = 0; t < 32; ++t) dcol2[t] *= s;  // row `lane` of s*D, packed

    // ---- build half-split operands ----
    // dA[t] = row `lane`, own half (j = 32h+2t, +1).
    // dB[t] = row `lane^32`, own half: my pairs for the OTHER half are
    // exactly what the partner needs, and vice versa (D symmetric) -> one
    // permlane32 exchange per component (one-time, VALU pipe).
    #pragma unroll
    for (int t = 0; t < 16; ++t) {
      dA[t] = h ? dcol2[16 + t] : dcol2[t];
      f32x2 cx = h ? dcol2[t] : dcol2[16 + t];   // my pairs, other half
      f32x2 r;
      r.x = xchg32(cx.x);
      r.y = xchg32(cx.y);
      dB[t] = r;
    }

    // ---- prologue: k = 1 directly (X0 = 0 -> x1 = mu, x2 = relu(-2 mu)) ----
    // Write ring row 0 of buffer 0, then issue the half-broadcast reads that
    // iteration u=1 will consume (same-wave DS ops in-order: RAW safe).
    x1 = mu;
    x2 = fmaxf(-2.0f * mu, 0.f);
    X1R[0][0][lane] = x1;
    X2R[0][0][lane] = x2 - bl;
    {
      const f32x4* bp = (const f32x4*)(&X1R[0][0][0] + h * 32);
      #pragma unroll
      for (int t = 0; t < 8; ++t) xb[t] = bp[t];
    }
  }

  // ---------- main loop: 40 phases x 25 iterations ----------
  #pragma unroll 1
  for (int p = 0; p < PHASES; ++p) {
    if (wv == 0) {
      float* rx1 = &X1R[p & 1][0][0];
      float* rx2 = &X2R[p & 1][0][0];
      #pragma unroll 1
      for (int u = (p == 0) ? 1 : 0; u < PLEN; ++u) {
        float ta = fmaf(s, x2, mu);
        // two 32-length dots over OWN half: row `lane` (A) and row
        // `lane^32` (B); 32 pk_fma total across 8 independent chains.
        f32x2 A0 = {0.f,0.f}, A1 = {0.f,0.f}, A2 = {0.f,0.f}, A3 = {0.f,0.f};
        f32x2 B0 = {0.f,0.f}, B1 = {0.f,0.f}, B2 = {0.f,0.f}, B3 = {0.f,0.f};
        #pragma unroll
        for (int t = 0; t < 8; t += 2) {
          A0 = fma2(dA[2*t + 0], xb[t].xy,     A0);
          A1 = fma2(dA[2*t + 1], xb[t].zw,     A1);
          A2 = fma2(dA[2*t + 2], xb[t + 1].xy, A2);
          A3 = fma2(dA[2*t + 3], xb[t + 1].zw, A3);
          B0 = fma2(dB[2*t + 0], xb[t].xy,     B0);
          B1 = fma2(dB[2*t + 1], xb[t].zw,     B1);
          B2 = fma2(dB[2*t + 2], xb[t + 1].xy, B2);
          B3 = fma2(dB[2*t + 3], xb[t + 1].zw, B3);
        }
        f32x2 RA = (A0 + A1) + (A2 + A3);
        f32x2 RB = (B0 + B1) + (B2 + B3);
        float pown = RA.x + RA.y;            // row lane, own half
        float poth = RB.x + RB.y;            // row lane^32, own half
        float prec = xchg32(poth);           // partner -> row lane, other half
        float x1n = (pown + prec) + ta;
        rx1[u * 64 + lane] = x1n;
        // issue next iteration's half-broadcast reads NOW (in-order DS pipe
        // sees the ring write above first); x2 tail hides part of the RT.
        {
          const f32x4* bp = (const f32x4*)(rx1 + u * 64 + h * 32);
          #pragma unroll
          for (int t = 0; t < 8; ++t) xb[t] = bp[t];
        }
        float x2n = fmaxf(fmaf(-2.0f, x1n, x1 + x2), 0.f);
        rx2[u * 64 + lane] = x2n - bl;
        x1 = x1n; x2 = x2n;
      }
    } else {
      if (p == 0) {
        // k = 0: X0 = 0 stores + primal_0 = Hinv @ (-b)
        Xp[lane] = 0.f;
        Xp[64 + lane] = 0.f;
        f32x2 pa = {0.f, 0.f}, pb = {0.f, 0.f};
        #pragma unroll
        for (int t = 0; t < 8; ++t) {
          f32x2 ta, tb;
          ta.x = -__shfl(bl, 32*h + 4*t + 0, 64);
          ta.y = -__shfl(bl, 32*h + 4*t + 1, 64);
          tb.x = -__shfl(bl, 32*h + 4*t + 2, 64);
          tb.y = -__shfl(bl, 32*h + 4*t + 3, 64);
          pa = fma2(hv2[2*t],     ta, pa);
          pb = fma2(hv2[2*t + 1], tb, pb);
        }
        float pr = (pa.x + pa.y) + (pb.x + pb.y);
        pr += __shfl_xor(pr, 32);
        if (h == 0) ob[i] = pr;
      } else {
        const float* rx1 = &X1R[(p - 1) & 1][0][0];
        const float* rx2 = &X2R[(p - 1) & 1][0][0];
        const int k0 = PLEN * (p - 1) + 1;
        float* Xk = Xp + (size_t)k0 * 128;
        float* obk = ob + (size_t)k0 * 32;
        #pragma unroll 1
        for (int u = 0; u < PLEN; ++u) {
          float x1v = rx1[u * 64 + lane];
          float x2mb = rx2[u * 64 + lane];
          Xk[u * 128 + lane] = x1v;
          Xk[u * 128 + 64 + lane] = x2mb + bl;
          const f32x4* tp = (const f32x4*)(rx2 + u * 64 + h * 32);
          f32x2 pa = {0.f, 0.f}, pb = {0.f, 0.f};
          #pragma unroll
          for (int t = 0; t < 8; ++t) {
            f32x4 tv = tp[t];
            pa = fma2(hv2[2*t],     tv.xy, pa);
            pb = fma2(hv2[2*t + 1], tv.zw, pb);
          }
          float pr = (pa.x + pa.y) + (pb.x + pb.y);
          pr += __shfl_xor(pr, 32);
          if (h == 0) obk[u * 32 + i] = pr;
        }
      }
    }
    __syncthreads();                      // both waves, every phase
  }

  if (wv == 1) {
    // tail: phase 39 data (buffer 1), k = 976..1000
    const float* rx1 = &X1R[1][0][0];
    const float* rx2 = &X2R[1][0][0];
    const int k0 = PLEN * (PHASES - 1) + 1;
    float* Xk = Xp + (size_t)k0 * 128;
    float* obk = ob + (size_t)k0 * 32;
    #pragma unroll 1
    for (int u = 0; u < PLEN; ++u) {
      float x1v = rx1[u * 64 + lane];
      float x2mb = rx2[u * 64 + lane];
      Xk[u * 128 + lane] = x1v;
      Xk[u * 128 + 64 + lane] = x2mb + bl;
      const f32x4* tp = (const f32x4*)(rx2 + u * 64 + h * 32);
      f32x2 pa = {0.f, 0.f}, pb = {0.f, 0.f};
      #pragma unroll
      for (int t = 0; t < 8; ++t) {
        f32x4 tv = tp[t];
        pa = fma2(hv2[2*t],     tv.xy, pa);
        pb = fma2(hv2[2*t + 1], tv.zw, pb);
      }
      float pr = (pa.x + pa.y) + (pb.x + pb.y);
      pr += __shfl_xor(pr, 32);
      if (h == 0) obk[u * 32 + i] = pr;
    }
  }
}

extern "C" void kernel_launch(void* const* d_in, const int* in_sizes, int n_in,
                              void* d_out, int out_size, void* d_ws, size_t ws_size,
                              hipStream_t stream) {
  (void)in_sizes; (void)n_in; (void)out_size; (void)d_ws; (void)ws_size;
  const float* q = (const float*)d_in[0];
  const float* b = (const float*)d_in[1];
  const float* P = (const float*)d_in[2];
  const float* H = (const float*)d_in[3];
  float* Xs = (float*)d_out;
  float* out2 = Xs + (size_t)BATCH * (ITERS + 1) * 128;

  fused_kernel<<<BATCH, 128, 0, stream>>>(q, b, P, H, Xs, out2);
}

// Round 8
// 710.668 us; speedup vs baseline: 1.2870x; 1.2870x over previous
//
#include <hip/hip_runtime.h>
#include <math.h>

#define BATCH 512
#define ITERS 1000
#define PLEN 20      // iterations per phase (even: 10 two-step pairs)
#define PHASES 50    // producer phase p covers k = 20p+1 .. 20p+20

typedef float f32x2 __attribute__((ext_vector_type(2)));
typedef float f32x4 __attribute__((ext_vector_type(4)));

// readlane requires a WAVE-UNIFORM lane index (compile-time constants below).
__device__ __forceinline__ float rdlane(float v, int l) {
  return __int_as_float(__builtin_amdgcn_readlane(__float_as_int(v), l));
}
__device__ __forceinline__ f32x2 fma2(f32x2 a, f32x2 b, f32x2 c) {
#if __has_builtin(__builtin_elementwise_fma)
  return __builtin_elementwise_fma(a, b, c);
#else
  f32x2 r; r.x = fmaf(a.x, b.x, c.x); r.y = fmaf(a.y, b.y, c.y); return r;
#endif
}

// sD row `lane` stored as 32 packed f32x2 (for v_pk_fma_f32). Element access
// (all indices compile-time constants in unrolled loops):
#define DC(c) (((c) & 1) ? dcol2[(c) >> 1].y : dcol2[(c) >> 1].x)

// Register-resident Gauss-Jordan on [A|I] (32x64); lane holds column `lane`.
#define GJ32_REG(g)                                            \
  _Pragma("unroll")                                            \
  for (int k = 0; k < 32; ++k) {                               \
    float inv = 1.0f / rdlane(g[k], k);                        \
    g[k] *= inv;                                               \
    _Pragma("unroll")                                          \
    for (int ii = 0; ii < 32; ++ii) {                          \
      if (ii == k) continue;                                   \
      float f = rdlane(g[ii], k);                              \
      g[ii] = fmaf(-f, g[k], g[ii]);                           \
    }                                                          \
  }

// wave 0 = iterator, wave 1 = consumer (Xs stores + primal GEMV + store).
// v9 = v6's two-step algebra x v3's prefetch skeleton.
// Evidence: v3's phase time == 25 x iterator serial chain (790 cyc/iter);
// the chain = one LDS write->read broadcast RT + wait + compute + tail per
// iteration. v6 proved the 2-step composition is numerically correct
// (passed, absmax 0.0156) but exposed per-group read latency by reading
// inline in the FMA loop (1536 cyc/iter). Here: ONE RT + ONE lgkm wait per
// TWO iterations; all 32 broadcast reads (x1 row + x2mb row) issued
// back-to-back after the ring writes into register arrays (v3 pattern),
// consumed next pair; 96 pk_fma in 12 independent chains stream behind the
// returning reads. Composition:
//   x1[k+2] = (sD)^2 x1[k] + s*(sD x2mb[k]) + s*x2[k+1] + c2,
//   c2 = s*(sD b) + sD mu + mu   (all precomputed; D^2 already computed
//   in setup for the power iteration). Consumer untouched (v4 lesson).
__global__ __launch_bounds__(128, 1)
void fused_kernel(const float* __restrict__ q,
                  const float* __restrict__ bmat,
                  const float* __restrict__ P,
                  const float* __restrict__ H,
                  float* __restrict__ Xs,
                  float* __restrict__ out2) {
  __shared__ __align__(16) float stage[2112];        // wave 1: Hl 64x33 -> HT 32x66
  __shared__ __align__(16) float X1R[2][PLEN][64];   // ring: x1
  __shared__ __align__(16) float X2R[2][PLEN][64];   // ring: x2 - b

  const int tid = threadIdx.x;
  const int wv = tid >> 6;          // 0 = iterator, 1 = consumer
  const int lane = tid & 63;
  const int row = blockIdx.x;
  const int i = lane & 31, h = lane >> 5;

  // ---- H row `lane` (both waves need it) ----
  float hreg[32];
  {
    const f32x4* hp = (const f32x4*)(H + lane * 32);
    #pragma unroll
    for (int j4 = 0; j4 < 8; ++j4) {
      f32x4 t = hp[j4];
      hreg[4*j4+0] = t.x; hreg[4*j4+1] = t.y; hreg[4*j4+2] = t.z; hreg[4*j4+3] = t.w;
    }
  }
  const float bl = bmat[row * 64 + lane];

  f32x2 dcol2[32];                  // iterator: row `lane` of sD (packed)
  f32x2 d2col2[32];                 // iterator: row `lane` of (sD)^2 (packed)
  float s = 0.f, mu = 0.f, c2 = 0.f;
  f32x4 xb1[16], xb2[16];           // broadcast x1[k], x2mb[k] (prefetched)
  float x1 = 0.f, x2 = 0.f;
  f32x2 hv2[16];                    // consumer state
  float* Xp = Xs + (size_t)row * (ITERS + 1) * 128;
  float* ob = out2 + (size_t)row * (ITERS + 1) * 32;

  // ---------- wave-1 Hinv transpose (block-wide barriers B1..B3) ----------
  if (wv == 1) {
    #pragma unroll
    for (int j = 0; j < 32; ++j) stage[lane * 33 + j] = hreg[j];
  }
  __syncthreads();                                // B1
  float gB[32];
  if (wv == 1) {
    float htc[64];                                // htc[m] = H[m][i]
    #pragma unroll
    for (int m = 0; m < 64; ++m) htc[m] = stage[m * 33 + i];
    #pragma unroll
    for (int r = 0; r < 32; ++r) {
      float a0 = 0.f, a1 = 0.f;
      #pragma unroll
      for (int m = 0; m < 64; m += 2) {
        a0 = fmaf(rdlane(hreg[r], m),     htc[m],     a0);
        a1 = fmaf(rdlane(hreg[r], m + 1), htc[m + 1], a1);
      }
      float hth = a0 + a1;                        // (H^T H)[r][i]
      gB[r] = (lane < 32) ? hth : (((lane - 32) == r) ? 1.0f : 0.0f);
    }
    GJ32_REG(gB)
  }
  __syncthreads();                                // B2
  if (wv == 1) {
    #pragma unroll
    for (int r = 0; r < 32; ++r) {                // Hinv[r][lane] -> staging
      float a0 = 0.f, a1 = 0.f;
      #pragma unroll
      for (int c = 0; c < 32; c += 2) {
        a0 = fmaf(rdlane(gB[r], 32 + c),     hreg[c],     a0);
        a1 = fmaf(rdlane(gB[r], 32 + c + 1), hreg[c + 1], a1);
      }
      stage[r * 66 + lane] = a0 + a1;
    }
  }
  __syncthreads();                                // B3
  if (wv == 1) {
    #pragma unroll
    for (int t = 0; t < 16; ++t)                  // lane (h,i): Hinv[i][32h+2t..+1]
      hv2[t] = *(const f32x2*)&stage[i * 66 + 32 * h + 2 * t];
  }

  if (wv == 0) {
    // ---------- setup (registers only): P^-1, P^-1 H^T, D, lambda_max ----------
    float pht[32], acc;
    float ecol[64];                 // D^2 column `lane` (reused for (sD)^2)
    {
      float g[32];
      #pragma unroll
      for (int r = 0; r < 32; ++r) {
        float pv = P[r * 32 + i];
        g[r] = (lane < 32) ? pv : (((lane - 32) == r) ? 1.0f : 0.0f);
      }
      GJ32_REG(g)
      #pragma unroll
      for (int r = 0; r < 32; ++r) {      // (P^-1 H^T)[r][lane]
        float a0 = 0.f, a1 = 0.f;
        #pragma unroll
        for (int j = 0; j < 32; j += 2) {
          a0 = fmaf(rdlane(g[r], 32 + j),     hreg[j],     a0);
          a1 = fmaf(rdlane(g[r], 32 + j + 1), hreg[j + 1], a1);
        }
        pht[r] = a0 + a1;
      }
    }
    {
      const float* qp = q + row * 32;     // wave-uniform -> s_loads
      float a0 = 0.f, a1 = 0.f;
      #pragma unroll
      for (int r = 0; r < 32; r += 2) {
        a0 = fmaf(qp[r],     pht[r],     a0);
        a1 = fmaf(qp[r + 1], pht[r + 1], a1);
      }
      acc = a0 + a1;                      // (H P^-1 q)[lane]
    }
    #pragma unroll
    for (int r = 0; r < 64; ++r) {        // D[r][lane] (symmetric)
      float a0 = 0.f, a1 = 0.f;
      #pragma unroll
      for (int j = 0; j < 32; j += 2) {
        a0 = fmaf(rdlane(hreg[j],     r), pht[j],     a0);
        a1 = fmaf(rdlane(hreg[j + 1], r), pht[j + 1], a1);
      }
      float val = a0 + a1;
      if (r & 1) dcol2[r >> 1].y = val; else dcol2[r >> 1].x = val;
    }
    {
      // ecol = D^2 column `lane` (squares power-iteration convergence; also
      // reused below as the (sD)^2 operator for the 2-step unroll)
      #pragma unroll
      for (int r = 0; r < 64; ++r) {
        float a0 = 0.f, a1 = 0.f;
        #pragma unroll
        for (int c = 0; c < 64; c += 2) {
          a0 = fmaf(rdlane(DC(r), c),     DC(c),     a0);
          a1 = fmaf(rdlane(DC(r), c + 1), DC(c + 1), a1);
        }
        ecol[r] = a0 + a1;
      }
      float v = 1.0f + 0.017f * (float)lane;
      #pragma unroll 1
      for (int t = 0; t < 112; ++t) {
        float a0 = 0.f, a1 = 0.f, a2 = 0.f, a3 = 0.f;
        #pragma unroll
        for (int c = 0; c < 64; c += 4) {
          a0 = fmaf(ecol[c+0], rdlane(v, c+0), a0);
          a1 = fmaf(ecol[c+1], rdlane(v, c+1), a1);
          a2 = fmaf(ecol[c+2], rdlane(v, c+2), a2);
          a3 = fmaf(ecol[c+3], rdlane(v, c+3), a3);
        }
        v = (a0 + a1) + (a2 + a3);
        if ((t & 7) == 7) {
          float n2 = v * v;
          #pragma unroll
          for (int m = 1; m < 64; m <<= 1) n2 += __shfl_xor(n2, m);
          v *= 1.0f / sqrtf(n2);
        }
      }
      float a0 = 0.f, a1 = 0.f, a2 = 0.f, a3 = 0.f;  // Rayleigh with D
      #pragma unroll
      for (int c = 0; c < 64; c += 4) {
        a0 = fmaf(DC(c+0), rdlane(v, c+0), a0);
        a1 = fmaf(DC(c+1), rdlane(v, c+1), a1);
        a2 = fmaf(DC(c+2), rdlane(v, c+2), a2);
        a3 = fmaf(DC(c+3), rdlane(v, c+3), a3);
      }
      float w = (a0 + a1) + (a2 + a3);
      float num = w * v, den = v * v;
      #pragma unroll
      for (int m = 1; m < 64; m <<= 1) {
        num += __shfl_xor(num, m);
        den += __shfl_xor(den, m);
      }
      s = den / num;                      // s = 1 / lambda_max(D)
    }
    mu = s * (acc - bl);
    #pragma unroll
    for (int t = 0; t < 32; ++t) dcol2[t] *= s;  // row `lane` of s*D, packed
    {
      const float s2 = s * s;             // (sD)^2 row, packed
      #pragma unroll
      for (int r = 0; r < 64; ++r) {
        float v = s2 * ecol[r];
        if (r & 1) d2col2[r >> 1].y = v; else d2col2[r >> 1].x = v;
      }
    }
    {
      // lane scalars: sdb = (sD b)[lane], sdmu = (sD mu_vec)[lane]
      float sdb = 0.f, sdmu = 0.f;
      #pragma unroll
      for (int c = 0; c < 64; c += 2) {
        sdb  = fmaf(DC(c),     rdlane(bl, c),     sdb);
        sdmu = fmaf(DC(c),     rdlane(mu, c),     sdmu);
        sdb  = fmaf(DC(c + 1), rdlane(bl, c + 1), sdb);
        sdmu = fmaf(DC(c + 1), rdlane(mu, c + 1), sdmu);
      }
      c2 = fmaf(s, sdb, sdmu) + mu;
    }
    // ---- prologue: virtual previous slot = state k=0 (x1=0, x2-b=-b);
    // write it, then issue the 32 broadcast reads pair 0 will consume
    // (same-wave DS ops are in-order: RAW safe). x1=x2=0 already.
    X1R[1][PLEN - 1][lane] = 0.f;
    X2R[1][PLEN - 1][lane] = -bl;
    {
      const f32x4* b1 = (const f32x4*)&X1R[1][PLEN - 1][0];  // uniform: bcast
      #pragma unroll
      for (int t = 0; t < 16; ++t) xb1[t] = b1[t];
      const f32x4* b2 = (const f32x4*)&X2R[1][PLEN - 1][0];
      #pragma unroll
      for (int t = 0; t < 16; ++t) xb2[t] = b2[t];
    }
  }

  // ---------- main loop: 50 phases x 10 two-step pairs ----------
  #pragma unroll 1
  for (int p = 0; p < PHASES; ++p) {
    if (wv == 0) {
      float* rx1 = &X1R[p & 1][0][0];
      float* rx2 = &X2R[p & 1][0][0];
      #pragma unroll 1
      for (int j = 0; j < PLEN / 2; ++j) {
        // m1 = sD x1[k] (A), m2 = (sD)^2 x1[k] (B), m3 = sD x2mb[k] (C):
        // 96 pk_fma in 12 independent chains, consuming the prefetched
        // xb1/xb2 in their read-issue order (fine-grained lgkm streaming).
        f32x2 A0={0.f,0.f},A1={0.f,0.f},A2={0.f,0.f},A3={0.f,0.f};
        f32x2 B0={0.f,0.f},B1={0.f,0.f},B2={0.f,0.f},B3={0.f,0.f};
        f32x2 C0={0.f,0.f},C1={0.f,0.f},C2={0.f,0.f},C3={0.f,0.f};
        #pragma unroll
        for (int t = 0; t < 16; t += 2) {
          A0 = fma2(dcol2[2*t + 0],  xb1[t].xy,     A0);
          A1 = fma2(dcol2[2*t + 1],  xb1[t].zw,     A1);
          B0 = fma2(d2col2[2*t + 0], xb1[t].xy,     B0);
          B1 = fma2(d2col2[2*t + 1], xb1[t].zw,     B1);
          A2 = fma2(dcol2[2*t + 2],  xb1[t + 1].xy, A2);
          A3 = fma2(dcol2[2*t + 3],  xb1[t + 1].zw, A3);
          B2 = fma2(d2col2[2*t + 2], xb1[t + 1].xy, B2);
          B3 = fma2(d2col2[2*t + 3], xb1[t + 1].zw, B3);
        }
        #pragma unroll
        for (int t = 0; t < 16; t += 2) {
          C0 = fma2(dcol2[2*t + 0], xb2[t].xy,     C0);
          C1 = fma2(dcol2[2*t + 1], xb2[t].zw,     C1);
          C2 = fma2(dcol2[2*t + 2], xb2[t + 1].xy, C2);
          C3 = fma2(dcol2[2*t + 3], xb2[t + 1].zw, C3);
        }
        f32x2 RA = (A0 + A1) + (A2 + A3); float m1 = RA.x + RA.y;
        f32x2 RB = (B0 + B1) + (B2 + B3); float m2 = RB.x + RB.y;
        f32x2 RC = (C0 + C1) + (C2 + C3); float m3 = RC.x + RC.y;
        // step k+1
        float x1k1 = m1 + fmaf(s, x2, mu);
        float x2k1 = fmaxf(fmaf(-2.0f, x1k1, x1 + x2), 0.f);
        // step k+2 (composed)
        float x1k2 = fmaf(s, m3 + x2k1, m2 + c2);
        float x2k2 = fmaxf(fmaf(-2.0f, x1k2, x1k1 + x2k1), 0.f);
        // ring writes (slots 2j, 2j+1), then issue next pair's broadcast
        // reads as one block (v3 skeleton: in-order DS pipe sees the writes
        // first; reads land in registers consumed next pair).
        rx1[(2*j)     * 64 + lane] = x1k1;
        rx2[(2*j)     * 64 + lane] = x2k1 - bl;
        rx1[(2*j + 1) * 64 + lane] = x1k2;
        rx2[(2*j + 1) * 64 + lane] = x2k2 - bl;
        {
          const f32x4* b1 = (const f32x4*)(rx1 + (2*j + 1) * 64);
          #pragma unroll
          for (int t = 0; t < 16; ++t) xb1[t] = b1[t];
          const f32x4* b2 = (const f32x4*)(rx2 + (2*j + 1) * 64);
          #pragma unroll
          for (int t = 0; t < 16; ++t) xb2[t] = b2[t];
        }
        x1 = x1k2; x2 = x2k2;
      }
    } else {
      if (p == 0) {
        // k = 0: X0 = 0 stores + primal_0 = Hinv @ (-b)
        Xp[lane] = 0.f;
        Xp[64 + lane] = 0.f;
        f32x2 pa = {0.f, 0.f}, pb = {0.f, 0.f};
        #pragma unroll
        for (int t = 0; t < 8; ++t) {
          f32x2 ta, tb;
          ta.x = -__shfl(bl, 32*h + 4*t + 0, 64);
          ta.y = -__shfl(bl, 32*h + 4*t + 1, 64);
          tb.x = -__shfl(bl, 32*h + 4*t + 2, 64);
          tb.y = -__shfl(bl, 32*h + 4*t + 3, 64);
          pa = fma2(hv2[2*t],     ta, pa);
          pb = fma2(hv2[2*t + 1], tb, pb);
        }
        float pr = (pa.x + pa.y) + (pb.x + pb.y);
        pr += __shfl_xor(pr, 32);
        if (h == 0) ob[i] = pr;
      } else {
        const float* rx1 = &X1R[(p - 1) & 1][0][0];
        const float* rx2 = &X2R[(p - 1) & 1][0][0];
        const int k0 = PLEN * (p - 1) + 1;
        float* Xk = Xp + (size_t)k0 * 128;
        float* obk = ob + (size_t)k0 * 32;
        #pragma unroll 1
        for (int u = 0; u < PLEN; ++u) {
          float x1v = rx1[u * 64 + lane];
          float x2mb = rx2[u * 64 + lane];
          Xk[u * 128 + lane] = x1v;
          Xk[u * 128 + 64 + lane] = x2mb + bl;
          const f32x4* tp = (const f32x4*)(rx2 + u * 64 + h * 32);
          f32x2 pa = {0.f, 0.f}, pb = {0.f, 0.f};
          #pragma unroll
          for (int t = 0; t < 8; ++t) {
            f32x4 tv = tp[t];
            pa = fma2(hv2[2*t],     tv.xy, pa);
            pb = fma2(hv2[2*t + 1], tv.zw, pb);
          }
          float pr = (pa.x + pa.y) + (pb.x + pb.y);
          pr += __shfl_xor(pr, 32);
          if (h == 0) obk[u * 32 + i] = pr;
        }
      }
    }
    __syncthreads();                      // both waves, every phase
  }

  if (wv == 1) {
    // tail: phase 49 data (buffer 1), k = 981..1000
    const float* rx1 = &X1R[1][0][0];
    const float* rx2 = &X2R[1][0][0];
    const int k0 = PLEN * (PHASES - 1) + 1;
    float* Xk = Xp + (size_t)k0 * 128;
    float* obk = ob + (size_t)k0 * 32;
    #pragma unroll 1
    for (int u = 0; u < PLEN; ++u) {
      float x1v = rx1[u * 64 + lane];
      float x2mb = rx2[u * 64 + lane];
      Xk[u * 128 + lane] = x1v;
      Xk[u * 128 + 64 + lane] = x2mb + bl;
      const f32x4* tp = (const f32x4*)(rx2 + u * 64 + h * 32);
      f32x2 pa = {0.f, 0.f}, pb = {0.f, 0.f};
      #pragma unroll
      for (int t = 0; t < 8; ++t) {
        f32x4 tv = tp[t];
        pa = fma2(hv2[2*t],     tv.xy, pa);
        pb = fma2(hv2[2*t + 1], tv.zw, pb);
      }
      float pr = (pa.x + pa.y) + (pb.x + pb.y);
      pr += __shfl_xor(pr, 32);
      if (h == 0) obk[u * 32 + i] = pr;
    }
  }
}

extern "C" void kernel_launch(void* const* d_in, const int* in_sizes, int n_in,
                              void* d_out, int out_size, void* d_ws, size_t ws_size,
                              hipStream_t stream) {
  (void)in_sizes; (void)n_in; (void)out_size; (void)d_ws; (void)ws_size;
  const float* q = (const float*)d_in[0];
  const float* b = (const float*)d_in[1];
  const float* P = (const float*)d_in[2];
  const float* H = (const float*)d_in[3];
  float* Xs = (float*)d_out;
  float* out2 = Xs + (size_t)BATCH * (ITERS + 1) * 128;

  fused_kernel<<<BATCH, 128, 0, stream>>>(q, b, P, H, Xs, out2);
}

// Round 9
// 680.840 us; speedup vs baseline: 1.3434x; 1.0438x over previous
//
#include <hip/hip_runtime.h>
#include <math.h>

#define BATCH 512
#define ITERS 1000
#define PLEN 20      // iterations per phase (even: 10 two-step pairs)
#define PHASES 50    // producer phase p covers k = 20p+1 .. 20p+20

typedef float f32x2 __attribute__((ext_vector_type(2)));
typedef float f32x4 __attribute__((ext_vector_type(4)));

// readlane requires a WAVE-UNIFORM lane index (compile-time constants below).
__device__ __forceinline__ float rdlane(float v, int l) {
  return __int_as_float(__builtin_amdgcn_readlane(__float_as_int(v), l));
}
__device__ __forceinline__ f32x2 fma2(f32x2 a, f32x2 b, f32x2 c) {
#if __has_builtin(__builtin_elementwise_fma)
  return __builtin_elementwise_fma(a, b, c);
#else
  f32x2 r; r.x = fmaf(a.x, b.x, c.x); r.y = fmaf(a.y, b.y, c.y); return r;
#endif
}

// sD row `lane` stored as 32 packed f32x2 (for v_pk_fma_f32). Element access
// (all indices compile-time constants in unrolled loops):
#define DC(c) (((c) & 1) ? dcol2[(c) >> 1].y : dcol2[(c) >> 1].x)

// Register-resident Gauss-Jordan on [A|I] (32x64); lane holds column `lane`.
#define GJ32_REG(g)                                            \
  _Pragma("unroll")                                            \
  for (int k = 0; k < 32; ++k) {                               \
    float inv = 1.0f / rdlane(g[k], k);                        \
    g[k] *= inv;                                               \
    _Pragma("unroll")                                          \
    for (int ii = 0; ii < 32; ++ii) {                          \
      if (ii == k) continue;                                   \
      float f = rdlane(g[ii], k);                              \
      g[ii] = fmaf(-f, g[k], g[ii]);                           \
    }                                                          \
  }

// wave 0 = iterator, wave 1 = consumer (Xs stores + primal GEMV + store).
// v10 = v9's two-step algebra with the load schedule FORCED.
// v9 diagnosis: VGPR_Count=192 < the >=256 live set the prefetch needs ->
// LLVM sank the 32 broadcast reads to their uses (pressure heuristic),
// exposing the LDS round-trip (v6 failure mode reproduced). Fix:
//  - xb1 (x1[k], 16 b128) prefetched across the pair boundary (v3 pattern,
//    only 64 VGPRs pending -> below the sinking threshold).
//  - xb2 (x2mb[k], 16 b128) issued MID-pair after A/B consumed xb1 (xb1
//    regs dead there -> allocator overlays xb2; peak ~230 VGPR), fenced
//    with sched_barrier(0) on both sides so the scheduler can neither
//    hoist it into A/B nor sink it into C.
// Composition (verified correct in v6/v9):
//   x1[k+2] = (sD)^2 x1[k] + s*(sD x2mb[k]) + s*x2[k+1] + c2,
//   c2 = s*(sD b) + (sD mu) + mu. Consumer untouched (v4 lesson).
__global__ __launch_bounds__(128, 1)
void fused_kernel(const float* __restrict__ q,
                  const float* __restrict__ bmat,
                  const float* __restrict__ P,
                  const float* __restrict__ H,
                  float* __restrict__ Xs,
                  float* __restrict__ out2) {
  __shared__ __align__(16) float stage[2112];        // wave 1: Hl 64x33 -> HT 32x66
  __shared__ __align__(16) float X1R[2][PLEN][64];   // ring: x1
  __shared__ __align__(16) float X2R[2][PLEN][64];   // ring: x2 - b

  const int tid = threadIdx.x;
  const int wv = tid >> 6;          // 0 = iterator, 1 = consumer
  const int lane = tid & 63;
  const int row = blockIdx.x;
  const int i = lane & 31, h = lane >> 5;

  // ---- H row `lane` (both waves need it) ----
  float hreg[32];
  {
    const f32x4* hp = (const f32x4*)(H + lane * 32);
    #pragma unroll
    for (int j4 = 0; j4 < 8; ++j4) {
      f32x4 t = hp[j4];
      hreg[4*j4+0] = t.x; hreg[4*j4+1] = t.y; hreg[4*j4+2] = t.z; hreg[4*j4+3] = t.w;
    }
  }
  const float bl = bmat[row * 64 + lane];

  f32x2 dcol2[32];                  // iterator: row `lane` of sD (packed)
  f32x2 d2col2[32];                 // iterator: row `lane` of (sD)^2 (packed)
  float s = 0.f, mu = 0.f, c2 = 0.f;
  f32x4 xb1[16];                    // broadcast x1[k] (prefetched cross-pair)
  float x1 = 0.f, x2 = 0.f;
  f32x2 hv2[16];                    // consumer state
  float* Xp = Xs + (size_t)row * (ITERS + 1) * 128;
  float* ob = out2 + (size_t)row * (ITERS + 1) * 32;

  // ---------- wave-1 Hinv transpose (block-wide barriers B1..B3) ----------
  if (wv == 1) {
    #pragma unroll
    for (int j = 0; j < 32; ++j) stage[lane * 33 + j] = hreg[j];
  }
  __syncthreads();                                // B1
  float gB[32];
  if (wv == 1) {
    float htc[64];                                // htc[m] = H[m][i]
    #pragma unroll
    for (int m = 0; m < 64; ++m) htc[m] = stage[m * 33 + i];
    #pragma unroll
    for (int r = 0; r < 32; ++r) {
      float a0 = 0.f, a1 = 0.f;
      #pragma unroll
      for (int m = 0; m < 64; m += 2) {
        a0 = fmaf(rdlane(hreg[r], m),     htc[m],     a0);
        a1 = fmaf(rdlane(hreg[r], m + 1), htc[m + 1], a1);
      }
      float hth = a0 + a1;                        // (H^T H)[r][i]
      gB[r] = (lane < 32) ? hth : (((lane - 32) == r) ? 1.0f : 0.0f);
    }
    GJ32_REG(gB)
  }
  __syncthreads();                                // B2
  if (wv == 1) {
    #pragma unroll
    for (int r = 0; r < 32; ++r) {                // Hinv[r][lane] -> staging
      float a0 = 0.f, a1 = 0.f;
      #pragma unroll
      for (int c = 0; c < 32; c += 2) {
        a0 = fmaf(rdlane(gB[r], 32 + c),     hreg[c],     a0);
        a1 = fmaf(rdlane(gB[r], 32 + c + 1), hreg[c + 1], a1);
      }
      stage[r * 66 + lane] = a0 + a1;
    }
  }
  __syncthreads();                                // B3
  if (wv == 1) {
    #pragma unroll
    for (int t = 0; t < 16; ++t)                  // lane (h,i): Hinv[i][32h+2t..+1]
      hv2[t] = *(const f32x2*)&stage[i * 66 + 32 * h + 2 * t];
  }

  if (wv == 0) {
    // ---------- setup (registers only): P^-1, P^-1 H^T, D, lambda_max ----------
    float pht[32], acc;
    float ecol[64];                 // D^2 column `lane` (reused for (sD)^2)
    {
      float g[32];
      #pragma unroll
      for (int r = 0; r < 32; ++r) {
        float pv = P[r * 32 + i];
        g[r] = (lane < 32) ? pv : (((lane - 32) == r) ? 1.0f : 0.0f);
      }
      GJ32_REG(g)
      #pragma unroll
      for (int r = 0; r < 32; ++r) {      // (P^-1 H^T)[r][lane]
        float a0 = 0.f, a1 = 0.f;
        #pragma unroll
        for (int j = 0; j < 32; j += 2) {
          a0 = fmaf(rdlane(g[r], 32 + j),     hreg[j],     a0);
          a1 = fmaf(rdlane(g[r], 32 + j + 1), hreg[j + 1], a1);
        }
        pht[r] = a0 + a1;
      }
    }
    {
      const float* qp = q + row * 32;     // wave-uniform -> s_loads
      float a0 = 0.f, a1 = 0.f;
      #pragma unroll
      for (int r = 0; r < 32; r += 2) {
        a0 = fmaf(qp[r],     pht[r],     a0);
        a1 = fmaf(qp[r + 1], pht[r + 1], a1);
      }
      acc = a0 + a1;                      // (H P^-1 q)[lane]
    }
    #pragma unroll
    for (int r = 0; r < 64; ++r) {        // D[r][lane] (symmetric)
      float a0 = 0.f, a1 = 0.f;
      #pragma unroll
      for (int j = 0; j < 32; j += 2) {
        a0 = fmaf(rdlane(hreg[j],     r), pht[j],     a0);
        a1 = fmaf(rdlane(hreg[j + 1], r), pht[j + 1], a1);
      }
      float val = a0 + a1;
      if (r & 1) dcol2[r >> 1].y = val; else dcol2[r >> 1].x = val;
    }
    {
      // ecol = D^2 column `lane` (squares power-iteration convergence; also
      // reused below as the (sD)^2 operator for the 2-step unroll)
      #pragma unroll
      for (int r = 0; r < 64; ++r) {
        float a0 = 0.f, a1 = 0.f;
        #pragma unroll
        for (int c = 0; c < 64; c += 2) {
          a0 = fmaf(rdlane(DC(r), c),     DC(c),     a0);
          a1 = fmaf(rdlane(DC(r), c + 1), DC(c + 1), a1);
        }
        ecol[r] = a0 + a1;
      }
      float v = 1.0f + 0.017f * (float)lane;
      #pragma unroll 1
      for (int t = 0; t < 112; ++t) {
        float a0 = 0.f, a1 = 0.f, a2 = 0.f, a3 = 0.f;
        #pragma unroll
        for (int c = 0; c < 64; c += 4) {
          a0 = fmaf(ecol[c+0], rdlane(v, c+0), a0);
          a1 = fmaf(ecol[c+1], rdlane(v, c+1), a1);
          a2 = fmaf(ecol[c+2], rdlane(v, c+2), a2);
          a3 = fmaf(ecol[c+3], rdlane(v, c+3), a3);
        }
        v = (a0 + a1) + (a2 + a3);
        if ((t & 7) == 7) {
          float n2 = v * v;
          #pragma unroll
          for (int m = 1; m < 64; m <<= 1) n2 += __shfl_xor(n2, m);
          v *= 1.0f / sqrtf(n2);
        }
      }
      float a0 = 0.f, a1 = 0.f, a2 = 0.f, a3 = 0.f;  // Rayleigh with D
      #pragma unroll
      for (int c = 0; c < 64; c += 4) {
        a0 = fmaf(DC(c+0), rdlane(v, c+0), a0);
        a1 = fmaf(DC(c+1), rdlane(v, c+1), a1);
        a2 = fmaf(DC(c+2), rdlane(v, c+2), a2);
        a3 = fmaf(DC(c+3), rdlane(v, c+3), a3);
      }
      float w = (a0 + a1) + (a2 + a3);
      float num = w * v, den = v * v;
      #pragma unroll
      for (int m = 1; m < 64; m <<= 1) {
        num += __shfl_xor(num, m);
        den += __shfl_xor(den, m);
      }
      s = den / num;                      // s = 1 / lambda_max(D)
    }
    mu = s * (acc - bl);
    #pragma unroll
    for (int t = 0; t < 32; ++t) dcol2[t] *= s;  // row `lane` of s*D, packed
    {
      const float s2 = s * s;             // (sD)^2 row, packed
      #pragma unroll
      for (int r = 0; r < 64; ++r) {
        float v = s2 * ecol[r];
        if (r & 1) d2col2[r >> 1].y = v; else d2col2[r >> 1].x = v;
      }
    }
    {
      // lane scalars: sdb = (sD b)[lane], sdmu = (sD mu_vec)[lane]
      float sdb = 0.f, sdmu = 0.f;
      #pragma unroll
      for (int c = 0; c < 64; c += 2) {
        sdb  = fmaf(DC(c),     rdlane(bl, c),     sdb);
        sdmu = fmaf(DC(c),     rdlane(mu, c),     sdmu);
        sdb  = fmaf(DC(c + 1), rdlane(bl, c + 1), sdb);
        sdmu = fmaf(DC(c + 1), rdlane(mu, c + 1), sdmu);
      }
      c2 = fmaf(s, sdb, sdmu) + mu;
    }
    // ---- prologue: virtual previous slot = state k=0 (x1=0, x2-b=-b);
    // write it, then issue ONLY the x1 broadcast reads pair 0 will consume
    // (same-wave DS ops in-order: RAW safe). x1=x2=0 already.
    X1R[1][PLEN - 1][lane] = 0.f;
    X2R[1][PLEN - 1][lane] = -bl;
    {
      const f32x4* b1 = (const f32x4*)&X1R[1][PLEN - 1][0];  // uniform: bcast
      #pragma unroll
      for (int t = 0; t < 16; ++t) xb1[t] = b1[t];
    }
  }

  // ---------- main loop: 50 phases x 10 two-step pairs ----------
  #pragma unroll 1
  for (int p = 0; p < PHASES; ++p) {
    if (wv == 0) {
      float* rx1 = &X1R[p & 1][0][0];
      float* rx2 = &X2R[p & 1][0][0];
      // x2mb[k] source for pair 0 = last slot of the other buffer
      const f32x4* pb2 = (const f32x4*)&X2R[(p ^ 1) & 1][PLEN - 1][0];
      #pragma unroll 1
      for (int j = 0; j < PLEN / 2; ++j) {
        // ---- A/B: m1 = sD x1[k], m2 = (sD)^2 x1[k] off prefetched xb1 ----
        f32x2 A0={0.f,0.f},A1={0.f,0.f},A2={0.f,0.f},A3={0.f,0.f};
        f32x2 B0={0.f,0.f},B1={0.f,0.f},B2={0.f,0.f},B3={0.f,0.f};
        #pragma unroll
        for (int t = 0; t < 16; t += 2) {
          A0 = fma2(dcol2[2*t + 0],  xb1[t].xy,     A0);
          A1 = fma2(dcol2[2*t + 1],  xb1[t].zw,     A1);
          B0 = fma2(d2col2[2*t + 0], xb1[t].xy,     B0);
          B1 = fma2(d2col2[2*t + 1], xb1[t].zw,     B1);
          A2 = fma2(dcol2[2*t + 2],  xb1[t + 1].xy, A2);
          A3 = fma2(dcol2[2*t + 3],  xb1[t + 1].zw, A3);
          B2 = fma2(d2col2[2*t + 2], xb1[t + 1].xy, B2);
          B3 = fma2(d2col2[2*t + 3], xb1[t + 1].zw, B3);
        }
        f32x2 RA = (A0 + A1) + (A2 + A3); float m1 = RA.x + RA.y;
        f32x2 RB = (B0 + B1) + (B2 + B3); float m2 = RB.x + RB.y;
        // step k+1 (x1k1 output + elementwise x2k1)
        float x1k1 = m1 + fmaf(s, x2, mu);
        float x2k1 = fmaxf(fmaf(-2.0f, x1k1, x1 + x2), 0.f);
        // ---- xb2 issue, fenced: not hoistable into A/B (pressure), not
        // sinkable into C (exposure). xb1 regs are dead here -> overlay. ----
        __builtin_amdgcn_sched_barrier(0);
        f32x4 xb2[16];
        #pragma unroll
        for (int t = 0; t < 16; ++t) xb2[t] = pb2[t];
        __builtin_amdgcn_sched_barrier(0);
        // ---- C: m3 = sD x2mb[k] ----
        f32x2 C0={0.f,0.f},C1={0.f,0.f},C2={0.f,0.f},C3={0.f,0.f};
        #pragma unroll
        for (int t = 0; t < 16; t += 2) {
          C0 = fma2(dcol2[2*t + 0], xb2[t].xy,     C0);
          C1 = fma2(dcol2[2*t + 1], xb2[t].zw,     C1);
          C2 = fma2(dcol2[2*t + 2], xb2[t + 1].xy, C2);
          C3 = fma2(dcol2[2*t + 3], xb2[t + 1].zw, C3);
        }
        f32x2 RC = (C0 + C1) + (C2 + C3); float m3 = RC.x + RC.y;
        // step k+2 (composed)
        float x1k2 = fmaf(s, m3 + x2k1, m2 + c2);
        float x2k2 = fmaxf(fmaf(-2.0f, x1k2, x1k1 + x2k1), 0.f);
        // ring writes (slots 2j, 2j+1), then issue next pair's xb1 reads
        // (v3 skeleton: in-order DS pipe sees the writes first; reads land
        // in registers consumed next pair).
        rx1[(2*j)     * 64 + lane] = x1k1;
        rx2[(2*j)     * 64 + lane] = x2k1 - bl;
        rx1[(2*j + 1) * 64 + lane] = x1k2;
        rx2[(2*j + 1) * 64 + lane] = x2k2 - bl;
        {
          const f32x4* b1 = (const f32x4*)(rx1 + (2*j + 1) * 64);
          #pragma unroll
          for (int t = 0; t < 16; ++t) xb1[t] = b1[t];
        }
        pb2 = (const f32x4*)(rx2 + (2*j + 1) * 64);
        x1 = x1k2; x2 = x2k2;
      }
    } else {
      if (p == 0) {
        // k = 0: X0 = 0 stores + primal_0 = Hinv @ (-b)
        Xp[lane] = 0.f;
        Xp[64 + lane] = 0.f;
        f32x2 pa = {0.f, 0.f}, pb = {0.f, 0.f};
        #pragma unroll
        for (int t = 0; t < 8; ++t) {
          f32x2 ta, tb;
          ta.x = -__shfl(bl, 32*h + 4*t + 0, 64);
          ta.y = -__shfl(bl, 32*h + 4*t + 1, 64);
          tb.x = -__shfl(bl, 32*h + 4*t + 2, 64);
          tb.y = -__shfl(bl, 32*h + 4*t + 3, 64);
          pa = fma2(hv2[2*t],     ta, pa);
          pb = fma2(hv2[2*t + 1], tb, pb);
        }
        float pr = (pa.x + pa.y) + (pb.x + pb.y);
        pr += __shfl_xor(pr, 32);
        if (h == 0) ob[i] = pr;
      } else {
        const float* rx1 = &X1R[(p - 1) & 1][0][0];
        const float* rx2 = &X2R[(p - 1) & 1][0][0];
        const int k0 = PLEN * (p - 1) + 1;
        float* Xk = Xp + (size_t)k0 * 128;
        float* obk = ob + (size_t)k0 * 32;
        #pragma unroll 1
        for (int u = 0; u < PLEN; ++u) {
          float x1v = rx1[u * 64 + lane];
          float x2mb = rx2[u * 64 + lane];
          Xk[u * 128 + lane] = x1v;
          Xk[u * 128 + 64 + lane] = x2mb + bl;
          const f32x4* tp = (const f32x4*)(rx2 + u * 64 + h * 32);
          f32x2 pa = {0.f, 0.f}, pb = {0.f, 0.f};
          #pragma unroll
          for (int t = 0; t < 8; ++t) {
            f32x4 tv = tp[t];
            pa = fma2(hv2[2*t],     tv.xy, pa);
            pb = fma2(hv2[2*t + 1], tv.zw, pb);
          }
          float pr = (pa.x + pa.y) + (pb.x + pb.y);
          pr += __shfl_xor(pr, 32);
          if (h == 0) obk[u * 32 + i] = pr;
        }
      }
    }
    __syncthreads();                      // both waves, every phase
  }

  if (wv == 1) {
    // tail: phase 49 data (buffer 1), k = 981..1000
    const float* rx1 = &X1R[1][0][0];
    const float* rx2 = &X2R[1][0][0];
    const int k0 = PLEN * (PHASES - 1) + 1;
    float* Xk = Xp + (size_t)k0 * 128;
    float* obk = ob + (size_t)k0 * 32;
    #pragma unroll 1
    for (int u = 0; u < PLEN; ++u) {
      float x1v = rx1[u * 64 + lane];
      float x2mb = rx2[u * 64 + lane];
      Xk[u * 128 + lane] = x1v;
      Xk[u * 128 + 64 + lane] = x2mb + bl;
      const f32x4* tp = (const f32x4*)(rx2 + u * 64 + h * 32);
      f32x2 pa = {0.f, 0.f}, pb = {0.f, 0.f};
      #pragma unroll
      for (int t = 0; t < 8; ++t) {
        f32x4 tv = tp[t];
        pa = fma2(hv2[2*t],     tv.xy, pa);
        pb = fma2(hv2[2*t + 1], tv.zw, pb);
      }
      float pr = (pa.x + pa.y) + (pb.x + pb.y);
      pr += __shfl_xor(pr, 32);
      if (h == 0) obk[u * 32 + i] = pr;
    }
  }
}

extern "C" void kernel_launch(void* const* d_in, const int* in_sizes, int n_in,
                              void* d_out, int out_size, void* d_ws, size_t ws_size,
                              hipStream_t stream) {
  (void)in_sizes; (void)n_in; (void)out_size; (void)d_ws; (void)ws_size;
  const float* q = (const float*)d_in[0];
  const float* b = (const float*)d_in[1];
  const float* P = (const float*)d_in[2];
  const float* H = (const float*)d_in[3];
  float* Xs = (float*)d_out;
  float* out2 = Xs + (size_t)BATCH * (ITERS + 1) * 128;

  fused_kernel<<<BATCH, 128, 0, stream>>>(q, b, P, H, Xs, out2);
}

// Round 10
// 578.968 us; speedup vs baseline: 1.5798x; 1.1760x over previous
//
#include <hip/hip_runtime.h>
#include <math.h>

#define BATCH 512
#define ITERS 1000
#define PLEN 25      // iterations per phase
#define PHASES 40    // producer phase p covers k = 25p+1 .. 25p+25

typedef float f32x2 __attribute__((ext_vector_type(2)));
typedef float f32x4 __attribute__((ext_vector_type(4)));

// readlane requires a WAVE-UNIFORM lane index (compile-time constants below).
__device__ __forceinline__ float rdlane(float v, int l) {
  return __int_as_float(__builtin_amdgcn_readlane(__float_as_int(v), l));
}
__device__ __forceinline__ f32x2 fma2(f32x2 a, f32x2 b, f32x2 c) {
#if __has_builtin(__builtin_elementwise_fma)
  return __builtin_elementwise_fma(a, b, c);
#else
  f32x2 r; r.x = fmaf(a.x, b.x, c.x); r.y = fmaf(a.y, b.y, c.y); return r;
#endif
}

// sD row `lane` stored as 32 packed f32x2 (for v_pk_fma_f32). Element access
// for the setup code (all indices compile-time constants in unrolled loops):
#define DC(c) (((c) & 1) ? dcol2[(c) >> 1].y : dcol2[(c) >> 1].x)

// Register-resident Gauss-Jordan on [A|I] (32x64); lane holds column `lane`.
#define GJ32_REG(g)                                            \
  _Pragma("unroll")                                            \
  for (int k = 0; k < 32; ++k) {                               \
    float inv = 1.0f / rdlane(g[k], k);                        \
    g[k] *= inv;                                               \
    _Pragma("unroll")                                          \
    for (int ii = 0; ii < 32; ++ii) {                          \
      if (ii == k) continue;                                   \
      float f = rdlane(g[ii], k);                              \
      g[ii] = fmaf(-f, g[k], g[ii]);                           \
    }                                                          \
  }

// wave 0 = iterator, wave 1 = consumer.
// v11 = v3 (the verified best, 329 us/dispatch) + iterator-owned Xs stores.
// Rationale: 7 structural rewrites all regressed; the consistent model is
// phase = max(iterator serial chain ~790cyc, DS-pipe occupancy ~672cyc/CU)
// -> 85% DS-pipe occupancy is the binding wall. This change cuts consumer
// DS reads 10->8 per iter (drops its 2 ring b32 reads; iterator stores
// x1n/x2n to Xs directly from registers) WITHOUT touching the iterator's
// proven 16-read prefetch window (v9/v10 lesson: any schedule with >~190
// live VGPRs gets its prefetch sunk by LLVM; v3's 156-VGPR pattern is the
// only one the scheduler respects). x1 ring collapses to one 64-float
// broadcast slot (consumer never reads x1 anymore).
__global__ __launch_bounds__(128, 1)
void fused_kernel(const float* __restrict__ q,
                  const float* __restrict__ bmat,
                  const float* __restrict__ P,
                  const float* __restrict__ H,
                  float* __restrict__ Xs,
                  float* __restrict__ out2) {
  __shared__ __align__(16) float stage[2112];        // wave 1: Hl 64x33 -> HT 32x66
  __shared__ __align__(16) float X1B[64];            // iterator broadcast slot
  __shared__ __align__(16) float X2R[2][PLEN][64];   // ring: x2 - b (GEMV input)

  const int tid = threadIdx.x;
  const int wv = tid >> 6;          // 0 = iterator, 1 = consumer
  const int lane = tid & 63;
  const int row = blockIdx.x;
  const int i = lane & 31, h = lane >> 5;

  // ---- H row `lane` (both waves need it) ----
  float hreg[32];
  {
    const f32x4* hp = (const f32x4*)(H + lane * 32);
    #pragma unroll
    for (int j4 = 0; j4 < 8; ++j4) {
      f32x4 t = hp[j4];
      hreg[4*j4+0] = t.x; hreg[4*j4+1] = t.y; hreg[4*j4+2] = t.z; hreg[4*j4+3] = t.w;
    }
  }
  const float bl = bmat[row * 64 + lane];

  f32x2 dcol2[32]; float s = 0.f, mu = 0.f;       // iterator state
  f32x4 xb[16];                                   // broadcast x1 (iterator)
  float x1 = 0.f, x2 = 0.f;
  f32x2 hv2[16];                                  // consumer state
  float* Xp = Xs + (size_t)row * (ITERS + 1) * 128;
  float* ob = out2 + (size_t)row * (ITERS + 1) * 32;

  // ---------- wave-1 Hinv transpose (block-wide barriers B1..B3) ----------
  if (wv == 1) {
    #pragma unroll
    for (int j = 0; j < 32; ++j) stage[lane * 33 + j] = hreg[j];
  }
  __syncthreads();                                // B1
  float gB[32];
  if (wv == 1) {
    float htc[64];                                // htc[m] = H[m][i]
    #pragma unroll
    for (int m = 0; m < 64; ++m) htc[m] = stage[m * 33 + i];
    #pragma unroll
    for (int r = 0; r < 32; ++r) {
      float a0 = 0.f, a1 = 0.f;
      #pragma unroll
      for (int m = 0; m < 64; m += 2) {
        a0 = fmaf(rdlane(hreg[r], m),     htc[m],     a0);
        a1 = fmaf(rdlane(hreg[r], m + 1), htc[m + 1], a1);
      }
      float hth = a0 + a1;                        // (H^T H)[r][i]
      gB[r] = (lane < 32) ? hth : (((lane - 32) == r) ? 1.0f : 0.0f);
    }
    GJ32_REG(gB)
  }
  __syncthreads();                                // B2
  if (wv == 1) {
    #pragma unroll
    for (int r = 0; r < 32; ++r) {                // Hinv[r][lane] -> staging
      float a0 = 0.f, a1 = 0.f;
      #pragma unroll
      for (int c = 0; c < 32; c += 2) {
        a0 = fmaf(rdlane(gB[r], 32 + c),     hreg[c],     a0);
        a1 = fmaf(rdlane(gB[r], 32 + c + 1), hreg[c + 1], a1);
      }
      stage[r * 66 + lane] = a0 + a1;
    }
  }
  __syncthreads();                                // B3
  if (wv == 1) {
    #pragma unroll
    for (int t = 0; t < 16; ++t)                  // lane (h,i): Hinv[i][32h+2t..+1]
      hv2[t] = *(const f32x2*)&stage[i * 66 + 32 * h + 2 * t];
  }

  if (wv == 0) {
    // ---------- setup (registers only): P^-1, P^-1 H^T, D, lambda_max ----------
    float pht[32], acc;
    {
      float g[32];
      #pragma unroll
      for (int r = 0; r < 32; ++r) {
        float pv = P[r * 32 + i];
        g[r] = (lane < 32) ? pv : (((lane - 32) == r) ? 1.0f : 0.0f);
      }
      GJ32_REG(g)
      #pragma unroll
      for (int r = 0; r < 32; ++r) {      // (P^-1 H^T)[r][lane]
        float a0 = 0.f, a1 = 0.f;
        #pragma unroll
        for (int j = 0; j < 32; j += 2) {
          a0 = fmaf(rdlane(g[r], 32 + j),     hreg[j],     a0);
          a1 = fmaf(rdlane(g[r], 32 + j + 1), hreg[j + 1], a1);
        }
        pht[r] = a0 + a1;
      }
    }
    {
      const float* qp = q + row * 32;     // wave-uniform -> s_loads
      float a0 = 0.f, a1 = 0.f;
      #pragma unroll
      for (int r = 0; r < 32; r += 2) {
        a0 = fmaf(qp[r],     pht[r],     a0);
        a1 = fmaf(qp[r + 1], pht[r + 1], a1);
      }
      acc = a0 + a1;                      // (H P^-1 q)[lane]
    }
    #pragma unroll
    for (int r = 0; r < 64; ++r) {        // D[r][lane] (symmetric)
      float a0 = 0.f, a1 = 0.f;
      #pragma unroll
      for (int j = 0; j < 32; j += 2) {
        a0 = fmaf(rdlane(hreg[j],     r), pht[j],     a0);
        a1 = fmaf(rdlane(hreg[j + 1], r), pht[j + 1], a1);
      }
      float val = a0 + a1;
      if (r & 1) dcol2[r >> 1].y = val; else dcol2[r >> 1].x = val;
    }
    {
      float ecol[64];                     // E = D^2 (squares convergence rate)
      #pragma unroll
      for (int r = 0; r < 64; ++r) {
        float a0 = 0.f, a1 = 0.f;
        #pragma unroll
        for (int c = 0; c < 64; c += 2) {
          a0 = fmaf(rdlane(DC(r), c),     DC(c),     a0);
          a1 = fmaf(rdlane(DC(r), c + 1), DC(c + 1), a1);
        }
        ecol[r] = a0 + a1;
      }
      float v = 1.0f + 0.017f * (float)lane;
      #pragma unroll 1
      for (int t = 0; t < 112; ++t) {
        float a0 = 0.f, a1 = 0.f, a2 = 0.f, a3 = 0.f;
        #pragma unroll
        for (int c = 0; c < 64; c += 4) {
          a0 = fmaf(ecol[c+0], rdlane(v, c+0), a0);
          a1 = fmaf(ecol[c+1], rdlane(v, c+1), a1);
          a2 = fmaf(ecol[c+2], rdlane(v, c+2), a2);
          a3 = fmaf(ecol[c+3], rdlane(v, c+3), a3);
        }
        v = (a0 + a1) + (a2 + a3);
        if ((t & 7) == 7) {
          float n2 = v * v;
          #pragma unroll
          for (int m = 1; m < 64; m <<= 1) n2 += __shfl_xor(n2, m);
          v *= 1.0f / sqrtf(n2);
        }
      }
      float a0 = 0.f, a1 = 0.f, a2 = 0.f, a3 = 0.f;  // Rayleigh with D
      #pragma unroll
      for (int c = 0; c < 64; c += 4) {
        a0 = fmaf(DC(c+0), rdlane(v, c+0), a0);
        a1 = fmaf(DC(c+1), rdlane(v, c+1), a1);
        a2 = fmaf(DC(c+2), rdlane(v, c+2), a2);
        a3 = fmaf(DC(c+3), rdlane(v, c+3), a3);
      }
      float w = (a0 + a1) + (a2 + a3);
      float num = w * v, den = v * v;
      #pragma unroll
      for (int m = 1; m < 64; m <<= 1) {
        num += __shfl_xor(num, m);
        den += __shfl_xor(den, m);
      }
      s = den / num;                      // s = 1 / lambda_max(D)
    }
    mu = s * (acc - bl);
    #pragma unroll
    for (int t = 0; t < 32; ++t) dcol2[t] *= s;  // row `lane` of s*D, packed

    // ---- prologue: k = 1 directly (X0 = 0 -> x1 = mu, x2 = relu(-2 mu)) ----
    // Write broadcast slot + ring slot 0 of buffer 0, issue the broadcast
    // reads iteration u=1 consumes (same-wave DS in-order: RAW safe), and
    // store Xs[k=1] directly (iterator owns Xs stores now).
    x1 = mu;
    x2 = fmaxf(-2.0f * mu, 0.f);
    X1B[lane] = x1;
    X2R[0][0][lane] = x2 - bl;
    {
      const f32x4* bp = (const f32x4*)&X1B[0];        // uniform addr: broadcast
      #pragma unroll
      for (int t = 0; t < 16; ++t) xb[t] = bp[t];
    }
    Xp[128 + lane] = x1;                  // Xs[k=1][0:64]
    Xp[128 + 64 + lane] = x2;             // Xs[k=1][64:128]
  }

  // ---------- main loop: 40 phases x 25 iterations ----------
  #pragma unroll 1
  for (int p = 0; p < PHASES; ++p) {
    if (wv == 0) {
      float* rx2 = &X2R[p & 1][0][0];
      #pragma unroll 1
      for (int u = (p == 0) ? 1 : 0; u < PLEN; ++u) {
        float ta = fmaf(s, x2, mu);
        f32x2 A0 = {0.f, 0.f}, A1 = {0.f, 0.f};
        f32x2 A2 = {0.f, 0.f}, A3 = {0.f, 0.f};
        // 32 packed FMAs: sD (packed pairs) * broadcast x1 (from X1B)
        #pragma unroll
        for (int t = 0; t < 16; t += 2) {
          A0 = fma2(dcol2[2*t + 0], xb[t].xy,     A0);
          A1 = fma2(dcol2[2*t + 1], xb[t].zw,     A1);
          A2 = fma2(dcol2[2*t + 2], xb[t + 1].xy, A2);
          A3 = fma2(dcol2[2*t + 3], xb[t + 1].zw, A3);
        }
        f32x2 R = (A0 + A1) + (A2 + A3);
        float x1n = (R.x + R.y) + ta;
        X1B[lane] = x1n;
        // issue next iteration's broadcast reads NOW (in-order DS pipe sees
        // the slot write above first); x2 tail + global stores below hide
        // part of the round-trip latency.
        {
          const f32x4* bp = (const f32x4*)&X1B[0];
          #pragma unroll
          for (int t = 0; t < 16; ++t) xb[t] = bp[t];
        }
        float x2n = fmaxf(fmaf(-2.0f, x1n, x1 + x2), 0.f);
        rx2[u * 64 + lane] = x2n - bl;
        // Xs[k] stores from registers (k = 25p + u + 1); coalesced b32 x2.
        {
          float* Xk = Xp + (size_t)(PLEN * p + u + 1) * 128;
          Xk[lane] = x1n;
          Xk[64 + lane] = x2n;
        }
        x1 = x1n; x2 = x2n;
      }
    } else {
      if (p == 0) {
        // k = 0: X0 = 0 stores + primal_0 = Hinv @ (-b)
        Xp[lane] = 0.f;
        Xp[64 + lane] = 0.f;
        f32x2 pa = {0.f, 0.f}, pb = {0.f, 0.f};
        #pragma unroll
        for (int t = 0; t < 8; ++t) {
          f32x2 ta, tb;
          ta.x = -__shfl(bl, 32*h + 4*t + 0, 64);
          ta.y = -__shfl(bl, 32*h + 4*t + 1, 64);
          tb.x = -__shfl(bl, 32*h + 4*t + 2, 64);
          tb.y = -__shfl(bl, 32*h + 4*t + 3, 64);
          pa = fma2(hv2[2*t],     ta, pa);
          pb = fma2(hv2[2*t + 1], tb, pb);
        }
        float pr = (pa.x + pa.y) + (pb.x + pb.y);
        pr += __shfl_xor(pr, 32);
        if (h == 0) ob[i] = pr;
      } else {
        // GEMV-only: primal_k = Hinv @ x2mb for k = 25(p-1)+1 .. +25
        const float* rx2 = &X2R[(p - 1) & 1][0][0];
        const int k0 = PLEN * (p - 1) + 1;
        float* obk = ob + (size_t)k0 * 32;
        #pragma unroll 1
        for (int u = 0; u < PLEN; ++u) {
          const f32x4* tp = (const f32x4*)(rx2 + u * 64 + h * 32);
          f32x2 pa = {0.f, 0.f}, pb = {0.f, 0.f};
          #pragma unroll
          for (int t = 0; t < 8; ++t) {
            f32x4 tv = tp[t];
            pa = fma2(hv2[2*t],     tv.xy, pa);
            pb = fma2(hv2[2*t + 1], tv.zw, pb);
          }
          float pr = (pa.x + pa.y) + (pb.x + pb.y);
          pr += __shfl_xor(pr, 32);
          if (h == 0) obk[u * 32 + i] = pr;
        }
      }
    }
    __syncthreads();                      // both waves, every phase
  }

  if (wv == 1) {
    // tail: phase 39 data (buffer 1), k = 976..1000 — GEMV only
    const float* rx2 = &X2R[1][0][0];
    const int k0 = PLEN * (PHASES - 1) + 1;
    float* obk = ob + (size_t)k0 * 32;
    #pragma unroll 1
    for (int u = 0; u < PLEN; ++u) {
      const f32x4* tp = (const f32x4*)(rx2 + u * 64 + h * 32);
      f32x2 pa = {0.f, 0.f}, pb = {0.f, 0.f};
      #pragma unroll
      for (int t = 0; t < 8; ++t) {
        f32x4 tv = tp[t];
        pa = fma2(hv2[2*t],     tv.xy, pa);
        pb = fma2(hv2[2*t + 1], tv.zw, pb);
      }
      float pr = (pa.x + pa.y) + (pb.x + pb.y);
      pr += __shfl_xor(pr, 32);
      if (h == 0) obk[u * 32 + i] = pr;
    }
  }
}

extern "C" void kernel_launch(void* const* d_in, const int* in_sizes, int n_in,
                              void* d_out, int out_size, void* d_ws, size_t ws_size,
                              hipStream_t stream) {
  (void)in_sizes; (void)n_in; (void)out_size; (void)d_ws; (void)ws_size;
  const float* q = (const float*)d_in[0];
  const float* b = (const float*)d_in[1];
  const float* P = (const float*)d_in[2];
  const float* H = (const float*)d_in[3];
  float* Xs = (float*)d_out;
  float* out2 = Xs + (size_t)BATCH * (ITERS + 1) * 128;

  fused_kernel<<<BATCH, 128, 0, stream>>>(q, b, P, H, Xs, out2);
}